// Round 16
// baseline (558.145 us; speedup 1.0000x reference)
//
#include <hip/hip_runtime.h>
#include <hip/hip_bf16.h>

#define N_NODES 50000
#define VOCAB   2048
#define HID     256
#define N_EDGES 1600000

typedef __attribute__((ext_vector_type(8))) __bf16 bf16x8;
typedef __attribute__((ext_vector_type(4))) __bf16 bf16x4;
typedef __attribute__((ext_vector_type(4))) float  f32x4;

// async global->LDS, 16B per lane (HW: lds dst = wave-uniform base + lane*16)
__device__ __forceinline__ void gl_lds16(const void* g, void* l) {
    __builtin_amdgcn_global_load_lds(
        (const __attribute__((address_space(1))) void*)g,
        (__attribute__((address_space(3))) void*)l, 16, 0, 0);
}

// ---------------------------------------------------------------------------
// L1: {zero cnt} || {cvt ctx_w -> bf16}   (R10-proven)
// ---------------------------------------------------------------------------
#define ZERO_NB 49
__global__ __launch_bounds__(256) void phase1(
    const float* __restrict__ w, __bf16* __restrict__ wb, int n4,
    int* __restrict__ cnt, int ncnt)
{
    int bid = blockIdx.x;
    if (bid < ZERO_NB) {
        const int base = bid * 1024 + threadIdx.x * 4;
        if (base + 3 < ncnt)      *(int4*)&cnt[base] = make_int4(0, 0, 0, 0);
        else                      for (int i = 0; i < 4; ++i)
                                      if (base + i < ncnt) cnt[base + i] = 0;
        return;
    }
    const int t = (bid - ZERO_NB) * 256 + threadIdx.x;
    if (t < n4) {
        const float4 v = ((const float4*)w)[t];
        bf16x4 p = { (__bf16)v.x, (__bf16)v.y, (__bf16)v.z, (__bf16)v.w };
        ((bf16x4*)wb)[t] = p;
    }
}

// ---------------------------------------------------------------------------
// L2: {hist} || {cvt out_w} || {gemm1}   (R10-proven, verbatim)
// ---------------------------------------------------------------------------
#define HIST_NB 96
#define CVTW_NB 64
__global__ __launch_bounds__(256) void phase2(
    const float*  __restrict__ Af,     // [M][2048] fp32 (context)
    const __bf16* __restrict__ Bb,     // [256][2048] bf16 (ctxw_b)
    __bf16*       __restrict__ Cb,     // [M][256] bf16 (support_b)
    int M,
    const int*    __restrict__ arow, int* __restrict__ cnt, int E,
    const float*  __restrict__ w2,   __bf16* __restrict__ w2b, int n4w)
{
    const int tid = threadIdx.x;
    int bid = blockIdx.x;

    if (bid < HIST_NB) {                    // ---- histogram (int4 reads) ----
        const int stride = HIST_NB * 256;
        for (int e4 = bid * 256 + tid; e4 < E / 4; e4 += stride) {
            const int4 r = ((const int4*)arow)[e4];
            atomicAdd(&cnt[r.x], 1); atomicAdd(&cnt[r.y], 1);
            atomicAdd(&cnt[r.z], 1); atomicAdd(&cnt[r.w], 1);
        }
        return;
    }
    bid -= HIST_NB;
    if (bid < CVTW_NB) {                    // ---- cvt out_w -> bf16 ----
        const int stride = CVTW_NB * 256;
        for (int t = bid * 256 + tid; t < n4w; t += stride) {
            const float4 v = ((const float4*)w2)[t];
            bf16x4 p = { (__bf16)v.x, (__bf16)v.y, (__bf16)v.z, (__bf16)v.w };
            ((bf16x4*)w2b)[t] = p;
        }
        return;
    }
    bid -= CVTW_NB;                         // ---- gemm1 ----

    constexpr int K = 2048, N = 256, BM = 64, BK = 32, nkt = K / BK;
    __shared__ float  sAf[3][BM * BK];     // 3 x  8 KB
    __shared__ __bf16 sB [3][N  * BK];     // 3 x 16 KB  (72 KB total)

    const int lane = tid & 63;
    const int wn   = tid >> 6;        // 0..3 (col-wave)
    const int half = lane >> 4;       // 0..3
    const int r16  = lane & 15;
    const int m0   = bid * BM;

    f32x4 acc[4][4] = {};

    auto stage = [&](int kt, int b) {   // 6 gl_lds per thread
        const int k0 = kt * BK;
        #pragma unroll
        for (int i = 0; i < 2; ++i) {   // A: 64 rows x 8 chunks(16B)
            const int s   = i * 256 + tid;
            const int row = s >> 3, c = s & 7;
            const int csw = c ^ (row & 7);
            int gr = m0 + row; if (gr >= M) gr = M - 1;
            gl_lds16(&Af[(size_t)gr * K + k0 + csw * 4], &sAf[b][s * 4]);
        }
        #pragma unroll
        for (int i = 0; i < 4; ++i) {   // B: 256 rows x 4 chunks(16B)
            const int s   = i * 256 + tid;
            const int row = s >> 2, c = s & 3;
            const int csw = c ^ (row & 3);
            gl_lds16(&Bb[(size_t)row * K + k0 + csw * 8], &sB[b][s * 8]);
        }
    };
    auto step = [&](int b) {
        bf16x8 bfr[4];
        #pragma unroll
        for (int n = 0; n < 4; ++n) {
            const int brow = wn * 64 + n * 16 + r16;
            bfr[n] = *(const bf16x8*)&sB[b][brow * 32 + (half ^ (brow & 3)) * 8];
        }
        #pragma unroll
        for (int m = 0; m < 4; ++m) {
            const int arw = m * 16 + r16;
            const int rx  = arw & 7;
            const f32x4 lo = *(const f32x4*)&sAf[b][arw * 32 + ((2 * half)     ^ rx) * 4];
            const f32x4 hi = *(const f32x4*)&sAf[b][arw * 32 + ((2 * half + 1) ^ rx) * 4];
            const bf16x8 af = { (__bf16)lo.x, (__bf16)lo.y, (__bf16)lo.z, (__bf16)lo.w,
                                (__bf16)hi.x, (__bf16)hi.y, (__bf16)hi.z, (__bf16)hi.w };
            #pragma unroll
            for (int n = 0; n < 4; ++n)
                acc[m][n] = __builtin_amdgcn_mfma_f32_16x16x32_bf16(
                                af, bfr[n], acc[m][n], 0, 0, 0);
        }
    };

    stage(0, 0);
    stage(1, 1);
    for (int t = 0; t < nkt; ++t) {
        if (t + 1 < nkt) asm volatile("s_waitcnt vmcnt(6)" ::: "memory");
        else             asm volatile("s_waitcnt vmcnt(0)" ::: "memory");
        __builtin_amdgcn_s_barrier();
        __builtin_amdgcn_sched_barrier(0);
        step(t % 3);
        if (t + 2 < nkt) stage(t + 2, (t + 2) % 3);
    }

    #pragma unroll
    for (int m = 0; m < 4; ++m) {
        #pragma unroll
        for (int j = 0; j < 4; ++j) {
            const int gr = m0 + m * 16 + half * 4 + j;
            if (gr >= M) continue;
            #pragma unroll
            for (int n = 0; n < 4; ++n) {
                const int gc = wn * 64 + n * 16 + r16;
                Cb[(size_t)gr * N + gc] = (__bf16)acc[m][n][j];
            }
        }
    }
}

// ---------------------------------------------------------------------------
// 2-phase coalesced scan (seeds cursor)
// ---------------------------------------------------------------------------
#define SCAN_NB 49      // 49 x 256 x 4 = 50176 >= 50000

__global__ __launch_bounds__(256) void scan1(
    const int* __restrict__ cnt, int* __restrict__ bsum, int n)
{
    __shared__ int red[256];
    const int base = blockIdx.x * 1024 + threadIdx.x * 4;
    int s = 0;
    #pragma unroll
    for (int i = 0; i < 4; ++i) { const int idx = base + i; if (idx < n) s += cnt[idx]; }
    red[threadIdx.x] = s;
    __syncthreads();
    for (int off = 128; off > 0; off >>= 1) {
        if (threadIdx.x < off) red[threadIdx.x] += red[threadIdx.x + off];
        __syncthreads();
    }
    if (threadIdx.x == 0) bsum[blockIdx.x] = red[0];
}

__global__ __launch_bounds__(256) void scan3m(
    const int* __restrict__ cnt, const int* __restrict__ bsum,
    int* __restrict__ ptr, int* __restrict__ cursor, int n, int E)
{
    __shared__ int hs[256];
    __shared__ int pre[256];
    const int tid = threadIdx.x;
    pre[tid] = (tid < blockIdx.x && tid < SCAN_NB) ? bsum[tid] : 0;
    __syncthreads();
    for (int off = 128; off > 0; off >>= 1) {
        if (tid < off) pre[tid] += pre[tid + off];
        __syncthreads();
    }
    const int bbase = pre[0];

    const int base = blockIdx.x * 1024 + tid * 4;
    int loc[4]; int s = 0;
    #pragma unroll
    for (int i = 0; i < 4; ++i) {
        const int idx = base + i;
        loc[i] = (idx < n) ? cnt[idx] : 0;
        s += loc[i];
    }
    hs[tid] = s;
    __syncthreads();
    for (int off = 1; off < 256; off <<= 1) {
        int v = (tid >= off) ? hs[tid - off] : 0;
        __syncthreads();
        hs[tid] += v;
        __syncthreads();
    }
    int run = bbase + ((tid == 0) ? 0 : hs[tid - 1]);
    #pragma unroll
    for (int i = 0; i < 4; ++i) {
        const int idx = base + i;
        if (idx < n) { ptr[idx] = run; cursor[idx] = run; }
        run += loc[i];
    }
    if (blockIdx.x == 0 && tid == 0) ptr[n] = E;
}

// ---------------------------------------------------------------------------
// csr_fill: 4 edges per thread (int4/float4 reads), scattered int2 writes
// ---------------------------------------------------------------------------
__global__ __launch_bounds__(256) void csr_fill(
    const int*   __restrict__ arow,
    const int*   __restrict__ acol,
    const float* __restrict__ aval,
    int*         __restrict__ cursor,
    int2*        __restrict__ cpair,
    int E)
{
    const int stride = gridDim.x * blockDim.x;
    for (int e4 = blockIdx.x * blockDim.x + threadIdx.x; e4 < E / 4; e4 += stride) {
        const int4   r = ((const int4*)arow)[e4];
        const int4   c = ((const int4*)acol)[e4];
        const float4 v = ((const float4*)aval)[e4];
        int p;
        p = atomicAdd(&cursor[r.x], 1); cpair[p] = make_int2(c.x, __float_as_int(v.x));
        p = atomicAdd(&cursor[r.y], 1); cpair[p] = make_int2(c.y, __float_as_int(v.y));
        p = atomicAdd(&cursor[r.z], 1); cpair[p] = make_int2(c.z, __float_as_int(v.z));
        p = atomicAdd(&cursor[r.w], 1); cpair[p] = make_int2(c.w, __float_as_int(v.w));
    }
}

// ---------------------------------------------------------------------------
// SpMM row body (device): one wave per row, 8-deep gather pipeline.
// ---------------------------------------------------------------------------
__device__ __forceinline__ void spmm_rows(
    int bid, int tid,
    const int*    __restrict__ ptr,
    const int2*   __restrict__ cpair,
    const __bf16* __restrict__ support,
    __bf16*       __restrict__ agg,
    int rowLo, int rowHi)
{
    const int lane = tid & 63;
    const int row  = rowLo + bid * 4 + (tid >> 6);
    if (row >= rowHi) return;
    const int l32 = lane & 31, ep = lane >> 5;
    const int beg = ptr[row], end = ptr[row + 1];

    float a[8] = {0.f, 0.f, 0.f, 0.f, 0.f, 0.f, 0.f, 0.f};

    auto fma8 = [&](float v, const uint4& s) {
        a[0] += v * __uint_as_float(s.x << 16);
        a[1] += v * __uint_as_float(s.x & 0xFFFF0000u);
        a[2] += v * __uint_as_float(s.y << 16);
        a[3] += v * __uint_as_float(s.y & 0xFFFF0000u);
        a[4] += v * __uint_as_float(s.z << 16);
        a[5] += v * __uint_as_float(s.z & 0xFFFF0000u);
        a[6] += v * __uint_as_float(s.w << 16);
        a[7] += v * __uint_as_float(s.w & 0xFFFF0000u);
    };

    int i = beg;
    for (; i + 16 <= end; i += 16) {
        int2 p[8];
        #pragma unroll
        for (int u = 0; u < 8; ++u) p[u] = cpair[i + 2 * u + ep];
        uint4 s[8];
        #pragma unroll
        for (int u = 0; u < 8; ++u)
            s[u] = *(const uint4*)&support[(size_t)p[u].x * HID + l32 * 8];
        #pragma unroll
        for (int u = 0; u < 8; ++u) fma8(__int_as_float(p[u].y), s[u]);
    }
    for (; i + 2 <= end; i += 2) {
        const int2 p = cpair[i + ep];
        const uint4 s = *(const uint4*)&support[(size_t)p.x * HID + l32 * 8];
        fma8(__int_as_float(p.y), s);
    }
    if (i < end && ep == 0) {
        const int2 p = cpair[i];
        const uint4 s = *(const uint4*)&support[(size_t)p.x * HID + l32 * 8];
        fma8(__int_as_float(p.y), s);
    }

    #pragma unroll
    for (int k = 0; k < 8; ++k) a[k] += __shfl_xor(a[k], 32);

    if (ep == 0) {
        bf16x8 o = { (__bf16)fmaxf(a[0], 0.f), (__bf16)fmaxf(a[1], 0.f),
                     (__bf16)fmaxf(a[2], 0.f), (__bf16)fmaxf(a[3], 0.f),
                     (__bf16)fmaxf(a[4], 0.f), (__bf16)fmaxf(a[5], 0.f),
                     (__bf16)fmaxf(a[6], 0.f), (__bf16)fmaxf(a[7], 0.f) };
        *(bf16x8*)&agg[(size_t)row * HID + l32 * 8] = o;
    }
}

// ---------------------------------------------------------------------------
// GEMM2 tile body (device): R10-proven triple-buffer vmcnt(4) structure,
// operating on m-tile range [tLo, tLo+nTiles) x 16 n-tiles.
// nBlocks = nTiles*16 must be divisible by 8 (XCD swizzle bijective).
// ---------------------------------------------------------------------------
__device__ __forceinline__ void gemm2_tile(
    int bid, int nBlocks, int tid,
    const __bf16* __restrict__ Ab,    // [M][256]
    const __bf16* __restrict__ Bb,    // [2048][256]
    const float*  __restrict__ bias,
    float*        __restrict__ C,     // [M][2048]
    int M, int tLo)
{
    constexpr int K = 256, N = 2048, BM = 128, BN = 128, BK = 32;
    constexpr int NBY = N / BN, nkt = K / BK;
    __shared__ __bf16 sA[3][BM * BK];   // 3 x 8 KB
    __shared__ __bf16 sB[3][BN * BK];   // 3 x 8 KB  (48 KB total)

    const int lane = tid & 63;
    const int wid  = tid >> 6;
    const int wm   = wid >> 1;
    const int wn   = wid & 1;
    const int half = lane >> 4;
    const int r16  = lane & 15;

    const int cpx = nBlocks >> 3;
    const int wg  = (bid & 7) * cpx + (bid >> 3);
    const int m0  = (tLo + wg / NBY) * BM;
    const int n0  = (wg % NBY) * BN;

    f32x4 acc[4][4] = {};

    auto stage = [&](int kt, int b) {
        const int k0 = kt * BK;
        #pragma unroll
        for (int i = 0; i < 2; ++i) {
            const int s   = i * 256 + tid;
            const int row = s >> 2, c = s & 3;
            const int csw = c ^ (row & 3);
            int gr = m0 + row; if (gr >= M) gr = M - 1;
            gl_lds16(&Ab[(size_t)gr * K + k0 + csw * 8], &sA[b][s * 8]);
        }
        #pragma unroll
        for (int i = 0; i < 2; ++i) {
            const int s   = i * 256 + tid;
            const int row = s >> 2, c = s & 3;
            const int csw = c ^ (row & 3);
            gl_lds16(&Bb[(size_t)(n0 + row) * K + k0 + csw * 8], &sB[b][s * 8]);
        }
    };
    auto step = [&](int b) {
        bf16x8 bfr[4];
        #pragma unroll
        for (int n = 0; n < 4; ++n) {
            const int brow = wn * 64 + n * 16 + r16;
            bfr[n] = *(const bf16x8*)&sB[b][brow * 32 + (half ^ (brow & 3)) * 8];
        }
        #pragma unroll
        for (int m = 0; m < 4; ++m) {
            const int arw = wm * 64 + m * 16 + r16;
            const bf16x8 af = *(const bf16x8*)&sA[b][arw * 32 + (half ^ (arw & 3)) * 8];
            #pragma unroll
            for (int n = 0; n < 4; ++n)
                acc[m][n] = __builtin_amdgcn_mfma_f32_16x16x32_bf16(
                                af, bfr[n], acc[m][n], 0, 0, 0);
        }
    };

    stage(0, 0);
    stage(1, 1);
    for (int t = 0; t < nkt; ++t) {
        if (t + 1 < nkt) asm volatile("s_waitcnt vmcnt(4)" ::: "memory");
        else             asm volatile("s_waitcnt vmcnt(0)" ::: "memory");
        __builtin_amdgcn_s_barrier();
        __builtin_amdgcn_sched_barrier(0);
        step(t % 3);
        if (t + 2 < nkt) stage(t + 2, (t + 2) % 3);
    }

    #pragma unroll
    for (int m = 0; m < 4; ++m) {
        #pragma unroll
        for (int j = 0; j < 4; ++j) {
            const int gr = m0 + wm * 64 + m * 16 + half * 4 + j;
            if (gr >= M) continue;
            #pragma unroll
            for (int n = 0; n < 4; ++n) {
                const int gc = n0 + wn * 64 + n * 16 + r16;
                __builtin_nontemporal_store(acc[m][n][j] + bias[gc],
                                            &C[(size_t)gr * N + gc]);
            }
        }
    }
}

// pure spmm (chunk 0)
__global__ __launch_bounds__(256) void spmm_k(
    const int* __restrict__ ptr, const int2* __restrict__ cpair,
    const __bf16* __restrict__ support, __bf16* __restrict__ agg,
    int rowLo, int rowHi)
{
    spmm_rows(blockIdx.x, threadIdx.x, ptr, cpair, support, agg, rowLo, rowHi);
}

// pure gemm2 (last chunk)
__global__ __launch_bounds__(256) void gemm2_k(
    const __bf16* __restrict__ Ab, const __bf16* __restrict__ Bb,
    const float* __restrict__ bias, float* __restrict__ C,
    int M, int tLo)
{
    gemm2_tile(blockIdx.x, gridDim.x, threadIdx.x, Ab, Bb, bias, C, M, tLo);
}

// merged: spmm chunk (first spmmNB blocks) || gemm2 chunk (rest)
__global__ __launch_bounds__(256) void spmm_gemm2_k(
    const int* __restrict__ ptr, const int2* __restrict__ cpair,
    const __bf16* __restrict__ support, __bf16* __restrict__ agg,
    int rowLo, int rowHi, int spmmNB,
    const __bf16* __restrict__ Ab, const __bf16* __restrict__ Bb,
    const float* __restrict__ bias, float* __restrict__ C,
    int M, int tLo, int g2NB)
{
    const int bid = blockIdx.x;
    if (bid < spmmNB) {
        spmm_rows(bid, threadIdx.x, ptr, cpair, support, agg, rowLo, rowHi);
        return;
    }
    gemm2_tile(bid - spmmNB, g2NB, threadIdx.x, Ab, Bb, bias, C, M, tLo);
}

extern "C" void kernel_launch(void* const* d_in, const int* in_sizes, int n_in,
                              void* d_out, int out_size, void* d_ws, size_t ws_size,
                              hipStream_t stream) {
    const float* context  = (const float*)d_in[0];
    const int*   adj_row  = (const int*)  d_in[1];
    const int*   adj_col  = (const int*)  d_in[2];
    const float* adj_val  = (const float*)d_in[3];
    const float* ctx_w    = (const float*)d_in[4];
    const float* out_w    = (const float*)d_in[5];
    const float* out_b    = (const float*)d_in[6];
    float*       out      = (float*)d_out;

    char* ws = (char*)d_ws;
    __bf16* support_b = (__bf16*)ws;  ws += (size_t)N_NODES * HID * 2;
    __bf16* agg_b     = (__bf16*)ws;  ws += (size_t)N_NODES * HID * 2;
    __bf16* ctxw_b    = (__bf16*)ws;  ws += (size_t)HID * VOCAB * 2;
    __bf16* outw_b    = (__bf16*)ws;  ws += (size_t)VOCAB * HID * 2;
    int*    csr_ptr   = (int*)ws;     ws += ((size_t)N_NODES + 16) * 4;
    int*    cnt       = (int*)ws;     ws += (size_t)N_NODES * 4;
    int*    cursor    = (int*)ws;     ws += (size_t)N_NODES * 4;
    int*    bsum      = (int*)ws;     ws += 320;
    int2*   cpair     = (int2*)ws;    ws += (size_t)N_EDGES * 8;

    constexpr int N4 = HID * VOCAB / 4;

    // L1: zero cnt || cvt ctx_w
    phase1<<<dim3(ZERO_NB + (N4 + 255) / 256), 256, 0, stream>>>(
        ctx_w, ctxw_b, N4, cnt, N_NODES);

    // L2: hist || cvt out_w || gemm1
    phase2<<<dim3(HIST_NB + CVTW_NB + (N_NODES + 63) / 64), 256, 0, stream>>>(
        context, ctxw_b, support_b, N_NODES,
        adj_row, cnt, N_EDGES,
        out_w, outw_b, N4);

    // L3-4: scan (ptr + cursor seed)
    scan1<<<SCAN_NB, 256, 0, stream>>>(cnt, bsum, N_NODES);
    scan3m<<<SCAN_NB, 256, 0, stream>>>(cnt, bsum, csr_ptr, cursor, N_NODES, N_EDGES);

    // L5: CSR fill
    csr_fill<<<512, 256, 0, stream>>>(
        adj_row, adj_col, adj_val, cursor, cpair, N_EDGES);

    // L6-9: 3-chunk spmm/gemm2 software pipeline (stream-ordered deps)
    constexpr int T0 = 130, T1 = 130, T2 = 131;          // m-tiles (sum 391)
    constexpr int R1 = T0 * 128;                          // 16640
    constexpr int R2 = (T0 + T1) * 128;                   // 33280
    constexpr int S0 = (R1 + 3) / 4;                      // 4160 spmm blocks
    constexpr int S1 = (R2 - R1 + 3) / 4;                 // 4160
    constexpr int S2 = (N_NODES - R2 + 3) / 4;            // 4180
    constexpr int G0 = T0 * 16, G1 = T1 * 16, G2 = T2 * 16; // 2080/2080/2096

    // spmm(c0)
    spmm_k<<<S0, 256, 0, stream>>>(csr_ptr, cpair, support_b, agg_b, 0, R1);
    // spmm(c1) || gemm2(c0)
    spmm_gemm2_k<<<S1 + G0, 256, 0, stream>>>(
        csr_ptr, cpair, support_b, agg_b, R1, R2, S1,
        agg_b, outw_b, out_b, out, N_NODES, 0, G0);
    // spmm(c2) || gemm2(c1)
    spmm_gemm2_k<<<S2 + G1, 256, 0, stream>>>(
        csr_ptr, cpair, support_b, agg_b, R2, N_NODES, S2,
        agg_b, outw_b, out_b, out, N_NODES, T0, G1);
    // gemm2(c2)
    gemm2_k<<<G2, 256, 0, stream>>>(
        agg_b, outw_b, out_b, out, N_NODES, T0 + T1);
}

// Round 17
// 490.007 us; speedup vs baseline: 1.1391x; 1.1391x over previous
//
#include <hip/hip_runtime.h>
#include <hip/hip_bf16.h>

#define N_NODES 50000
#define VOCAB   2048
#define HID     256
#define N_EDGES 1600000

typedef __attribute__((ext_vector_type(8))) __bf16 bf16x8;
typedef __attribute__((ext_vector_type(4))) __bf16 bf16x4;
typedef __attribute__((ext_vector_type(4))) float  f32x4;

// async global->LDS, 16B per lane (HW: lds dst = wave-uniform base + lane*16)
__device__ __forceinline__ void gl_lds16(const void* g, void* l) {
    __builtin_amdgcn_global_load_lds(
        (const __attribute__((address_space(1))) void*)g,
        (__attribute__((address_space(3))) void*)l, 16, 0, 0);
}

// ---------------------------------------------------------------------------
// L1: {zero cnt} || {cvt ctx_w -> bf16}   (R10-proven)
// ---------------------------------------------------------------------------
#define ZERO_NB 49
__global__ __launch_bounds__(256) void phase1(
    const float* __restrict__ w, __bf16* __restrict__ wb, int n4,
    int* __restrict__ cnt, int ncnt)
{
    int bid = blockIdx.x;
    if (bid < ZERO_NB) {
        const int base = bid * 1024 + threadIdx.x * 4;
        if (base + 3 < ncnt)      *(int4*)&cnt[base] = make_int4(0, 0, 0, 0);
        else                      for (int i = 0; i < 4; ++i)
                                      if (base + i < ncnt) cnt[base + i] = 0;
        return;
    }
    const int t = (bid - ZERO_NB) * 256 + threadIdx.x;
    if (t < n4) {
        const float4 v = ((const float4*)w)[t];
        bf16x4 p = { (__bf16)v.x, (__bf16)v.y, (__bf16)v.z, (__bf16)v.w };
        ((bf16x4*)wb)[t] = p;
    }
}

// ---------------------------------------------------------------------------
// L2: {hist} || {cvt out_w} || {gemm1}   — 512-thread blocks.
// gemm1: support_b[M][256] = bf16( context_f32[M][2048] @ ctxw_b^T )
//   BM=128, BN=256, BK=32, 8 waves (2x4, 64x64 each), double-buffered
//   gl_lds (64 KB -> 2 blocks/CU = 16 waves/CU), counted vmcnt(0) +
//   raw s_barrier per tile; stage(t+1) issued after barrier so it flies
//   under step(t). Halves B-side L2 traffic + load instrs vs BM=64.
// ---------------------------------------------------------------------------
#define HIST_NB 96
#define CVTW_NB 64
__global__ __launch_bounds__(512) void phase2(
    const float*  __restrict__ Af,     // [M][2048] fp32 (context)
    const __bf16* __restrict__ Bb,     // [256][2048] bf16 (ctxw_b)
    __bf16*       __restrict__ Cb,     // [M][256] bf16 (support_b)
    int M,
    const int*    __restrict__ arow, int* __restrict__ cnt, int E,
    const float*  __restrict__ w2,   __bf16* __restrict__ w2b, int n4w)
{
    const int tid = threadIdx.x;
    int bid = blockIdx.x;

    if (bid < HIST_NB) {                    // ---- histogram (int4 reads) ----
        const int stride = HIST_NB * 512;
        for (int e4 = bid * 512 + tid; e4 < E / 4; e4 += stride) {
            const int4 r = ((const int4*)arow)[e4];
            atomicAdd(&cnt[r.x], 1); atomicAdd(&cnt[r.y], 1);
            atomicAdd(&cnt[r.z], 1); atomicAdd(&cnt[r.w], 1);
        }
        return;
    }
    bid -= HIST_NB;
    if (bid < CVTW_NB) {                    // ---- cvt out_w -> bf16 ----
        const int stride = CVTW_NB * 512;
        for (int t = bid * 512 + tid; t < n4w; t += stride) {
            const float4 v = ((const float4*)w2)[t];
            bf16x4 p = { (__bf16)v.x, (__bf16)v.y, (__bf16)v.z, (__bf16)v.w };
            ((bf16x4*)w2b)[t] = p;
        }
        return;
    }
    bid -= CVTW_NB;                         // ---- gemm1 ----

    constexpr int K = 2048, N = 256, BM = 128, BK = 32, nkt = K / BK;
    __shared__ float  sAf[2][BM * BK];     // 2 x 16 KB
    __shared__ __bf16 sB [2][N  * BK];     // 2 x 16 KB  (64 KB total)

    const int lane = tid & 63;
    const int wid  = tid >> 6;        // 0..7
    const int wm   = wid >> 2;        // 0..1
    const int wn   = wid & 3;         // 0..3
    const int half = lane >> 4;       // 0..3
    const int r16  = lane & 15;
    const int m0   = bid * BM;

    f32x4 acc[4][4] = {};

    auto stage = [&](int kt, int b) {   // 4 gl_lds per thread
        const int k0 = kt * BK;
        #pragma unroll
        for (int i = 0; i < 2; ++i) {   // A: 128 rows x 8 chunks(16B) = 1024
            const int s   = i * 512 + tid;
            const int row = s >> 3, c = s & 7;
            const int csw = c ^ (row & 7);
            int gr = m0 + row; if (gr >= M) gr = M - 1;
            gl_lds16(&Af[(size_t)gr * K + k0 + csw * 4], &sAf[b][s * 4]);
        }
        #pragma unroll
        for (int i = 0; i < 2; ++i) {   // B: 256 rows x 4 chunks(16B) = 1024
            const int s   = i * 512 + tid;
            const int row = s >> 2, c = s & 3;
            const int csw = c ^ (row & 3);
            gl_lds16(&Bb[(size_t)row * K + k0 + csw * 8], &sB[b][s * 8]);
        }
    };
    auto step = [&](int b) {
        bf16x8 bfr[4];
        #pragma unroll
        for (int n = 0; n < 4; ++n) {
            const int brow = wn * 64 + n * 16 + r16;
            bfr[n] = *(const bf16x8*)&sB[b][brow * 32 + (half ^ (brow & 3)) * 8];
        }
        #pragma unroll
        for (int m = 0; m < 4; ++m) {
            const int arw = wm * 64 + m * 16 + r16;
            const int rx  = arw & 7;
            const f32x4 lo = *(const f32x4*)&sAf[b][arw * 32 + ((2 * half)     ^ rx) * 4];
            const f32x4 hi = *(const f32x4*)&sAf[b][arw * 32 + ((2 * half + 1) ^ rx) * 4];
            const bf16x8 af = { (__bf16)lo.x, (__bf16)lo.y, (__bf16)lo.z, (__bf16)lo.w,
                                (__bf16)hi.x, (__bf16)hi.y, (__bf16)hi.z, (__bf16)hi.w };
            #pragma unroll
            for (int n = 0; n < 4; ++n)
                acc[m][n] = __builtin_amdgcn_mfma_f32_16x16x32_bf16(
                                af, bfr[n], acc[m][n], 0, 0, 0);
        }
    };

    stage(0, 0);
    for (int t = 0; t < nkt; ++t) {
        const int cur = t & 1;
        asm volatile("s_waitcnt vmcnt(0)" ::: "memory");  // my tile-t loads done
        __builtin_amdgcn_s_barrier();                     // all waves' done
        __builtin_amdgcn_sched_barrier(0);
        if (t + 1 < nkt) stage(t + 1, cur ^ 1);           // flies under step(t)
        step(cur);
    }

    // epilogue: C/D layout col=lane&15, row=(lane>>4)*4+j (m89-verified)
    #pragma unroll
    for (int m = 0; m < 4; ++m) {
        #pragma unroll
        for (int j = 0; j < 4; ++j) {
            const int gr = m0 + wm * 64 + m * 16 + half * 4 + j;
            if (gr >= M) continue;
            #pragma unroll
            for (int n = 0; n < 4; ++n) {
                const int gc = wn * 64 + n * 16 + r16;
                Cb[(size_t)gr * N + gc] = (__bf16)acc[m][n][j];
            }
        }
    }
}

// ---------------------------------------------------------------------------
// 2-phase coalesced scan (seeds cursor)
// ---------------------------------------------------------------------------
#define SCAN_NB 49      // 49 x 256 x 4 = 50176 >= 50000

__global__ __launch_bounds__(256) void scan1(
    const int* __restrict__ cnt, int* __restrict__ bsum, int n)
{
    __shared__ int red[256];
    const int base = blockIdx.x * 1024 + threadIdx.x * 4;
    int s = 0;
    #pragma unroll
    for (int i = 0; i < 4; ++i) { const int idx = base + i; if (idx < n) s += cnt[idx]; }
    red[threadIdx.x] = s;
    __syncthreads();
    for (int off = 128; off > 0; off >>= 1) {
        if (threadIdx.x < off) red[threadIdx.x] += red[threadIdx.x + off];
        __syncthreads();
    }
    if (threadIdx.x == 0) bsum[blockIdx.x] = red[0];
}

__global__ __launch_bounds__(256) void scan3m(
    const int* __restrict__ cnt, const int* __restrict__ bsum,
    int* __restrict__ ptr, int* __restrict__ cursor, int n, int E)
{
    __shared__ int hs[256];
    __shared__ int pre[256];
    const int tid = threadIdx.x;
    pre[tid] = (tid < blockIdx.x && tid < SCAN_NB) ? bsum[tid] : 0;
    __syncthreads();
    for (int off = 128; off > 0; off >>= 1) {
        if (tid < off) pre[tid] += pre[tid + off];
        __syncthreads();
    }
    const int bbase = pre[0];

    const int base = blockIdx.x * 1024 + tid * 4;
    int loc[4]; int s = 0;
    #pragma unroll
    for (int i = 0; i < 4; ++i) {
        const int idx = base + i;
        loc[i] = (idx < n) ? cnt[idx] : 0;
        s += loc[i];
    }
    hs[tid] = s;
    __syncthreads();
    for (int off = 1; off < 256; off <<= 1) {
        int v = (tid >= off) ? hs[tid - off] : 0;
        __syncthreads();
        hs[tid] += v;
        __syncthreads();
    }
    int run = bbase + ((tid == 0) ? 0 : hs[tid - 1]);
    #pragma unroll
    for (int i = 0; i < 4; ++i) {
        const int idx = base + i;
        if (idx < n) { ptr[idx] = run; cursor[idx] = run; }
        run += loc[i];
    }
    if (blockIdx.x == 0 && tid == 0) ptr[n] = E;
}

// ---------------------------------------------------------------------------
// csr_fill: 4 edges per thread (int4/float4 reads), scattered int2 writes
// ---------------------------------------------------------------------------
__global__ __launch_bounds__(256) void csr_fill(
    const int*   __restrict__ arow,
    const int*   __restrict__ acol,
    const float* __restrict__ aval,
    int*         __restrict__ cursor,
    int2*        __restrict__ cpair,
    int E)
{
    const int stride = gridDim.x * blockDim.x;
    for (int e4 = blockIdx.x * blockDim.x + threadIdx.x; e4 < E / 4; e4 += stride) {
        const int4   r = ((const int4*)arow)[e4];
        const int4   c = ((const int4*)acol)[e4];
        const float4 v = ((const float4*)aval)[e4];
        int p;
        p = atomicAdd(&cursor[r.x], 1); cpair[p] = make_int2(c.x, __float_as_int(v.x));
        p = atomicAdd(&cursor[r.y], 1); cpair[p] = make_int2(c.y, __float_as_int(v.y));
        p = atomicAdd(&cursor[r.z], 1); cpair[p] = make_int2(c.z, __float_as_int(v.z));
        p = atomicAdd(&cursor[r.w], 1); cpair[p] = make_int2(c.w, __float_as_int(v.w));
    }
}

// ---------------------------------------------------------------------------
// SpMM gather + relu: one wave per row; 8-deep gather pipeline;
// __shfl_xor(32) fold; lanes 0-31 store bf16x8.
// ---------------------------------------------------------------------------
__global__ __launch_bounds__(256) void spmm_gather(
    const int*    __restrict__ ptr,
    const int2*   __restrict__ cpair,
    const __bf16* __restrict__ support,
    __bf16*       __restrict__ agg,
    int n)
{
    const int tid  = threadIdx.x;
    const int lane = tid & 63;
    const int row  = blockIdx.x * 4 + (tid >> 6);
    if (row >= n) return;
    const int l32 = lane & 31, ep = lane >> 5;
    const int beg = ptr[row], end = ptr[row + 1];

    float a[8] = {0.f, 0.f, 0.f, 0.f, 0.f, 0.f, 0.f, 0.f};

    auto fma8 = [&](float v, const uint4& s) {
        a[0] += v * __uint_as_float(s.x << 16);
        a[1] += v * __uint_as_float(s.x & 0xFFFF0000u);
        a[2] += v * __uint_as_float(s.y << 16);
        a[3] += v * __uint_as_float(s.y & 0xFFFF0000u);
        a[4] += v * __uint_as_float(s.z << 16);
        a[5] += v * __uint_as_float(s.z & 0xFFFF0000u);
        a[6] += v * __uint_as_float(s.w << 16);
        a[7] += v * __uint_as_float(s.w & 0xFFFF0000u);
    };

    int i = beg;
    for (; i + 16 <= end; i += 16) {
        int2 p[8];
        #pragma unroll
        for (int u = 0; u < 8; ++u) p[u] = cpair[i + 2 * u + ep];
        uint4 s[8];
        #pragma unroll
        for (int u = 0; u < 8; ++u)
            s[u] = *(const uint4*)&support[(size_t)p[u].x * HID + l32 * 8];
        #pragma unroll
        for (int u = 0; u < 8; ++u) fma8(__int_as_float(p[u].y), s[u]);
    }
    for (; i + 2 <= end; i += 2) {
        const int2 p = cpair[i + ep];
        const uint4 s = *(const uint4*)&support[(size_t)p.x * HID + l32 * 8];
        fma8(__int_as_float(p.y), s);
    }
    if (i < end && ep == 0) {
        const int2 p = cpair[i];
        const uint4 s = *(const uint4*)&support[(size_t)p.x * HID + l32 * 8];
        fma8(__int_as_float(p.y), s);
    }

    #pragma unroll
    for (int k = 0; k < 8; ++k) a[k] += __shfl_xor(a[k], 32);

    if (ep == 0) {
        bf16x8 o = { (__bf16)fmaxf(a[0], 0.f), (__bf16)fmaxf(a[1], 0.f),
                     (__bf16)fmaxf(a[2], 0.f), (__bf16)fmaxf(a[3], 0.f),
                     (__bf16)fmaxf(a[4], 0.f), (__bf16)fmaxf(a[5], 0.f),
                     (__bf16)fmaxf(a[6], 0.f), (__bf16)fmaxf(a[7], 0.f) };
        *(bf16x8*)&agg[(size_t)row * HID + l32 * 8] = o;
    }
}

// ---------------------------------------------------------------------------
// GEMM2 (R10-proven): out[M][2048] = agg_b @ outw_b^T + bias
// BM=128,BN=128,BK=32, 4 waves (2x2), triple-buffered gl_lds, vmcnt(4),
// XCD-chunked swizzle, nontemporal C stores.
// ---------------------------------------------------------------------------
__global__ __launch_bounds__(256) void gemm2(
    const __bf16* __restrict__ Ab,    // [M][256] bf16
    const __bf16* __restrict__ Bb,    // [2048][256] bf16
    const float*  __restrict__ bias,  // [2048]
    float*        __restrict__ C,     // [M][2048] fp32
    int M)
{
    constexpr int K = 256, N = 2048, BM = 128, BN = 128, BK = 32;
    constexpr int NBY = N / BN, nkt = K / BK;
    __shared__ __bf16 sA[3][BM * BK];   // 3 x 8 KB
    __shared__ __bf16 sB[3][BN * BK];   // 3 x 8 KB  (48 KB total)

    const int tid  = threadIdx.x;
    const int lane = tid & 63;
    const int wid  = tid >> 6;
    const int wm   = wid >> 1;
    const int wn   = wid & 1;
    const int half = lane >> 4;
    const int r16  = lane & 15;

    const int nwg = gridDim.x, cpx = nwg >> 3;
    const int wg  = (blockIdx.x & 7) * cpx + (blockIdx.x >> 3);
    const int m0  = (wg / NBY) * BM;
    const int n0  = (wg % NBY) * BN;

    f32x4 acc[4][4] = {};

    auto stage = [&](int kt, int b) {   // 4 gl_lds per thread
        const int k0 = kt * BK;
        #pragma unroll
        for (int i = 0; i < 2; ++i) {
            const int s   = i * 256 + tid;
            const int row = s >> 2, c = s & 3;
            const int csw = c ^ (row & 3);
            int gr = m0 + row; if (gr >= M) gr = M - 1;
            gl_lds16(&Ab[(size_t)gr * K + k0 + csw * 8], &sA[b][s * 8]);
        }
        #pragma unroll
        for (int i = 0; i < 2; ++i) {
            const int s   = i * 256 + tid;
            const int row = s >> 2, c = s & 3;
            const int csw = c ^ (row & 3);
            gl_lds16(&Bb[(size_t)(n0 + row) * K + k0 + csw * 8], &sB[b][s * 8]);
        }
    };
    auto step = [&](int b) {
        bf16x8 bfr[4];
        #pragma unroll
        for (int n = 0; n < 4; ++n) {
            const int brow = wn * 64 + n * 16 + r16;
            bfr[n] = *(const bf16x8*)&sB[b][brow * 32 + (half ^ (brow & 3)) * 8];
        }
        #pragma unroll
        for (int m = 0; m < 4; ++m) {
            const int arw = wm * 64 + m * 16 + r16;
            const bf16x8 af = *(const bf16x8*)&sA[b][arw * 32 + (half ^ (arw & 3)) * 8];
            #pragma unroll
            for (int n = 0; n < 4; ++n)
                acc[m][n] = __builtin_amdgcn_mfma_f32_16x16x32_bf16(
                                af, bfr[n], acc[m][n], 0, 0, 0);
        }
    };

    stage(0, 0);
    stage(1, 1);
    for (int t = 0; t < nkt; ++t) {
        if (t + 1 < nkt) asm volatile("s_waitcnt vmcnt(4)" ::: "memory");
        else             asm volatile("s_waitcnt vmcnt(0)" ::: "memory");
        __builtin_amdgcn_s_barrier();
        __builtin_amdgcn_sched_barrier(0);
        step(t % 3);
        if (t + 2 < nkt) stage(t + 2, (t + 2) % 3);
    }

    #pragma unroll
    for (int m = 0; m < 4; ++m) {
        #pragma unroll
        for (int j = 0; j < 4; ++j) {
            const int gr = m0 + wm * 64 + m * 16 + half * 4 + j;
            if (gr >= M) continue;
            #pragma unroll
            for (int n = 0; n < 4; ++n) {
                const int gc = n0 + wn * 64 + n * 16 + r16;
                __builtin_nontemporal_store(acc[m][n][j] + bias[gc],
                                            &C[(size_t)gr * N + gc]);
            }
        }
    }
}

extern "C" void kernel_launch(void* const* d_in, const int* in_sizes, int n_in,
                              void* d_out, int out_size, void* d_ws, size_t ws_size,
                              hipStream_t stream) {
    const float* context  = (const float*)d_in[0];
    const int*   adj_row  = (const int*)  d_in[1];
    const int*   adj_col  = (const int*)  d_in[2];
    const float* adj_val  = (const float*)d_in[3];
    const float* ctx_w    = (const float*)d_in[4];
    const float* out_w    = (const float*)d_in[5];
    const float* out_b    = (const float*)d_in[6];
    float*       out      = (float*)d_out;

    char* ws = (char*)d_ws;
    __bf16* support_b = (__bf16*)ws;  ws += (size_t)N_NODES * HID * 2;
    __bf16* agg_b     = (__bf16*)ws;  ws += (size_t)N_NODES * HID * 2;
    __bf16* ctxw_b    = (__bf16*)ws;  ws += (size_t)HID * VOCAB * 2;
    __bf16* outw_b    = (__bf16*)ws;  ws += (size_t)VOCAB * HID * 2;
    int*    csr_ptr   = (int*)ws;     ws += ((size_t)N_NODES + 16) * 4;
    int*    cnt       = (int*)ws;     ws += (size_t)N_NODES * 4;
    int*    cursor    = (int*)ws;     ws += (size_t)N_NODES * 4;
    int*    bsum      = (int*)ws;     ws += 320;
    int2*   cpair     = (int2*)ws;    ws += (size_t)N_EDGES * 8;

    constexpr int N4 = HID * VOCAB / 4;

    // L1: zero cnt || cvt ctx_w
    phase1<<<dim3(ZERO_NB + (N4 + 255) / 256), 256, 0, stream>>>(
        ctx_w, ctxw_b, N4, cnt, N_NODES);

    // L2: hist || cvt out_w || gemm1 (BM=128, 512 threads)
    phase2<<<dim3(HIST_NB + CVTW_NB + (N_NODES + 127) / 128), dim3(512), 0, stream>>>(
        context, ctxw_b, support_b, N_NODES,
        adj_row, cnt, N_EDGES,
        out_w, outw_b, N4);

    // L3-4: scan (ptr + cursor seed)
    scan1<<<SCAN_NB, 256, 0, stream>>>(cnt, bsum, N_NODES);
    scan3m<<<SCAN_NB, 256, 0, stream>>>(cnt, bsum, csr_ptr, cursor, N_NODES, N_EDGES);

    // L5: CSR fill
    csr_fill<<<512, 256, 0, stream>>>(
        adj_row, adj_col, adj_val, cursor, cpair, N_EDGES);

    // L6: SpMM gather + relu
    spmm_gather<<<(N_NODES + 3) / 4, 256, 0, stream>>>(
        csr_ptr, cpair, support_b, agg_b, N_NODES);

    // L7: GEMM2
    gemm2<<<dim3(((N_NODES + 127) / 128) * (VOCAB / 128)), 256, 0, stream>>>(
        agg_b, outw_b, out_b, out, N_NODES);
}